// Round 1
// baseline (948.108 us; speedup 1.0000x reference)
//
#include <hip/hip_runtime.h>

// y[n,o] = sum_r e[n,r]*(W[r]@x[n])[o] + (e@b)[n,o]
// Cast as one bf16 GEMM: A'[n, r*256+i] = e[n,r]*x[n,i]  (built on the fly),
// B^T = Wb[o][k] prepped once into d_ws (bf16), K extended by 64 to fold bias.

typedef __attribute__((ext_vector_type(4))) float f32x4;
typedef __attribute__((ext_vector_type(8))) short short8;
typedef __attribute__((ext_vector_type(8))) unsigned short ushort8;

#define R_DIM 32
#define I_DIM 256
#define O_DIM 256
#define KW    (R_DIM * I_DIM)   // 8192
#define KEXT  (KW + 64)         // 8256: [8192,8224)=b^T, [8224,8256)=0
#define BM    128
#define BN    256
#define BK    64
#define NT    (KEXT / BK)       // 129
#define NTHR  256

__device__ __forceinline__ unsigned short f2bf(float f) {
  unsigned u = __builtin_bit_cast(unsigned, f);
  u += 0x7FFFu + ((u >> 16) & 1u);            // RNE, inputs are normal floats
  return (unsigned short)(u >> 16);
}

__device__ __forceinline__ void gld_lds16(const void* g, void* l) {
  __builtin_amdgcn_global_load_lds(
      (const __attribute__((address_space(1))) unsigned int*)g,
      (__attribute__((address_space(3))) unsigned int*)l, 16, 0, 0);
}

// ---- prep: Wb[o][k] = bf16(W[r,o,i]) for k=r*256+i; bias block appended ----
__global__ void prep_w(const float* __restrict__ W, const float* __restrict__ b,
                       unsigned short* __restrict__ Wb) {
  const int id = blockIdx.x * 256 + threadIdx.x;   // 256*2064 threads exactly
  const int o  = id / (KEXT / 4);
  const int k4 = (id - o * (KEXT / 4)) * 4;
  float v[4];
  if (k4 < KW) {
    const int r = k4 >> 8, i = k4 & 255;
    const float4 w = *(const float4*)&W[((size_t)(r * O_DIM + o)) * I_DIM + i];
    v[0] = w.x; v[1] = w.y; v[2] = w.z; v[3] = w.w;
  } else {
#pragma unroll
    for (int t = 0; t < 4; ++t) {
      const int j = k4 + t - KW;
      v[t] = (j < R_DIM) ? b[j * O_DIM + o] : 0.f;
    }
  }
  uint2 pk;
  pk.x = (unsigned)f2bf(v[0]) | ((unsigned)f2bf(v[1]) << 16);
  pk.y = (unsigned)f2bf(v[2]) | ((unsigned)f2bf(v[3]) << 16);
  *(uint2*)&Wb[(size_t)o * KEXT + k4] = pk;
}

// ---- main GEMM: 256 thr, 4 waves (2x2), wave tile 64x128, acc[4][8] ----
template <bool USE_WS>
__global__ __launch_bounds__(NTHR, 2) void lkg_main(
    const float* __restrict__ x, const float* __restrict__ e,
    const float* __restrict__ Wf, const float* __restrict__ bf32,
    const unsigned short* __restrict__ Wb, float* __restrict__ out, int Ntot) {
  __shared__ unsigned short Alds[BM * BK];   // 16 KB
  __shared__ unsigned short Blds[BN * BK];   // 32 KB

  const int tid  = threadIdx.x;
  const int lane = tid & 63;
  const int wid  = tid >> 6;        // 0..3
  const int wr   = wid >> 1;        // 0..1
  const int wc   = wid & 1;         // 0..1
  const int l15  = lane & 15;
  const int lk8  = (lane >> 4) * 8;

  const int m0   = (int)blockIdx.x * BM;
  const int srow = tid >> 1;               // 0..127
  const int skq  = (tid & 1) * 32;         // 0 / 32
  const int gr   = min(m0 + srow, Ntot - 1);

  f32x4 acc[4][8];
#pragma unroll
  for (int a = 0; a < 4; ++a)
#pragma unroll
    for (int c = 0; c < 8; ++c) acc[a][c] = (f32x4){0.f, 0.f, 0.f, 0.f};

  for (int t = 0; t < NT; ++t) {
    const int k0 = t * BK;

    // ---------- A' staging: 32 elems/thread, issue x loads first ----------
    float av[32];
    if (k0 < KW) {
      const int r = k0 >> 8, i0 = k0 & 255;
      const float ev = e[(size_t)gr * R_DIM + r];
#pragma unroll
      for (int q = 0; q < 8; ++q) {
        const float4 xv = *(const float4*)&x[(size_t)gr * I_DIM + i0 + skq + q * 4];
        av[q * 4 + 0] = xv.x * ev; av[q * 4 + 1] = xv.y * ev;
        av[q * 4 + 2] = xv.z * ev; av[q * 4 + 3] = xv.w * ev;
      }
    } else {  // bias K-step: A' = e (cols 0..31), zeros after
#pragma unroll
      for (int s = 0; s < 32; ++s) {
        const int kk = skq + s;
        av[s] = (kk < R_DIM) ? e[(size_t)gr * R_DIM + kk] : 0.f;
      }
    }

    // ---------- B staging ----------
    if (USE_WS) {
      // async global->LDS, 16B/lane; wave w covers rows [w*64, w*64+64)
#pragma unroll
      for (int c = 0; c < 8; ++c) {
        const int o = wid * 64 + c * 8 + (lane >> 3);
        gld_lds16(Wb + (size_t)o * KEXT + k0 + (lane & 7) * 8,
                  &Blds[(wid * 64 + c * 8) * BK]);
      }
    } else {
      const int bo = tid;  // one B row per thread
      if (k0 < KW) {
        const int r = k0 >> 8, i0 = k0 & 255;
#pragma unroll
        for (int h = 0; h < 4; ++h) {
          float bv[16];
#pragma unroll
          for (int q = 0; q < 4; ++q) {
            const float4 wv =
                *(const float4*)&Wf[((size_t)(r * O_DIM + bo)) * I_DIM + i0 + h * 16 + q * 4];
            bv[q * 4 + 0] = wv.x; bv[q * 4 + 1] = wv.y;
            bv[q * 4 + 2] = wv.z; bv[q * 4 + 3] = wv.w;
          }
#pragma unroll
          for (int g2 = 0; g2 < 2; ++g2) {
            ushort8 pw;
#pragma unroll
            for (int j = 0; j < 8; ++j) pw[j] = f2bf(bv[g2 * 8 + j]);
            *(ushort8*)&Blds[bo * BK + h * 16 + g2 * 8] = pw;
          }
        }
      } else {
#pragma unroll
        for (int h = 0; h < 8; ++h) {
          ushort8 pw;
#pragma unroll
          for (int j = 0; j < 8; ++j) {
            const int kk = h * 8 + j;
            pw[j] = (kk < R_DIM) ? f2bf(bf32[kk * O_DIM + bo]) : (unsigned short)0;
          }
          *(ushort8*)&Blds[bo * BK + h * 8] = pw;
        }
      }
    }

    // ---------- A' scale/cvt/write (waits only on x loads; B glds stay in flight) ----------
#pragma unroll
    for (int h = 0; h < 4; ++h) {
      ushort8 pw;
#pragma unroll
      for (int j = 0; j < 8; ++j) pw[j] = f2bf(av[h * 8 + j]);
      *(ushort8*)&Alds[srow * BK + skq + h * 8] = pw;
    }

    __syncthreads();

    // ---------- compute: 64 MFMA / wave / K-step ----------
#pragma unroll
    for (int ks = 0; ks < 2; ++ks) {
      short8 af[4];
      short8 bfr[8];
#pragma unroll
      for (int fr = 0; fr < 4; ++fr)
        af[fr] = *(const short8*)&Alds[(wr * 64 + fr * 16 + l15) * BK + ks * 32 + lk8];
#pragma unroll
      for (int fc = 0; fc < 8; ++fc)
        bfr[fc] = *(const short8*)&Blds[(wc * 128 + fc * 16 + l15) * BK + ks * 32 + lk8];
#pragma unroll
      for (int fr = 0; fr < 4; ++fr)
#pragma unroll
        for (int fc = 0; fc < 8; ++fc)
          acc[fr][fc] =
              __builtin_amdgcn_mfma_f32_16x16x32_bf16(af[fr], bfr[fc], acc[fr][fc], 0, 0, 0);
    }

    __syncthreads();
  }

  // ---------- epilogue: C layout col=lane&15, row=(lane>>4)*4+j ----------
#pragma unroll
  for (int fr = 0; fr < 4; ++fr) {
    const int r0 = m0 + wr * 64 + fr * 16 + (lane >> 4) * 4;
#pragma unroll
    for (int fc = 0; fc < 8; ++fc) {
      const int col = wc * 128 + fc * 16 + l15;
#pragma unroll
      for (int j = 0; j < 4; ++j) {
        const int rr = r0 + j;
        if (rr < Ntot) out[(size_t)rr * O_DIM + col] = acc[fr][fc][j];
      }
    }
  }
}

extern "C" void kernel_launch(void* const* d_in, const int* in_sizes, int n_in,
                              void* d_out, int out_size, void* d_ws, size_t ws_size,
                              hipStream_t stream) {
  const float* x = (const float*)d_in[0];
  const float* e = (const float*)d_in[1];
  const float* W = (const float*)d_in[2];
  const float* b = (const float*)d_in[3];
  float* out = (float*)d_out;
  const int Ntot = in_sizes[0] / I_DIM;
  const int nb = (Ntot + BM - 1) / BM;

  const size_t wb_bytes = (size_t)O_DIM * KEXT * sizeof(unsigned short);
  if (ws_size >= wb_bytes) {
    unsigned short* Wb = (unsigned short*)d_ws;
    prep_w<<<(O_DIM * (KEXT / 4)) / 256, 256, 0, stream>>>(W, b, Wb);
    lkg_main<true><<<nb, NTHR, 0, stream>>>(x, e, W, b, Wb, out, Ntot);
  } else {
    lkg_main<false><<<nb, NTHR, 0, stream>>>(x, e, W, b, nullptr, out, Ntot);
  }
}

// Round 2
// 675.215 us; speedup vs baseline: 1.4042x; 1.4042x over previous
//
#include <hip/hip_runtime.h>

// y[n,o] = sum_r e[n,r]*(W[r]@x[n])[o] + (e@b)[n,o]
// One bf16 GEMM, K = 8256: k = il*64 + ih*32 + r (i = 128*ih + il), bias tile appended.
// A'[n,k] = e[n,r]*x[n,i] built on the fly (e-row in regs, x prefetched float4/4-tiles).
// B^T = Wb[o][k] bf16 in d_ws (row-major); LDS XOR-swizzled via pre-swizzled gld source.

typedef __attribute__((ext_vector_type(4))) float f32x4;
typedef __attribute__((ext_vector_type(8))) short short8;
typedef __attribute__((ext_vector_type(8))) unsigned short ushort8;

#define R_DIM 32
#define I_DIM 256
#define O_DIM 256
#define KW    8192
#define KEXT  8256            // +64: [8192,8224)=b^T, rest 0
#define BM    224
#define BN    256
#define BK    64
#define NT    (KEXT / BK)     // 129
#define NTHR  512

__device__ __forceinline__ unsigned short f2bf(float f) {
  unsigned u = __builtin_bit_cast(unsigned, f);
  u += 0x7FFFu + ((u >> 16) & 1u);  // RNE
  return (unsigned short)(u >> 16);
}

__device__ __forceinline__ void gld_lds16(const void* g, void* l) {
  __builtin_amdgcn_global_load_lds(
      (const __attribute__((address_space(1))) unsigned int*)g,
      (__attribute__((address_space(3))) unsigned int*)l, 16, 0, 0);
}

// ---- prep: Wb[o][k] = bf16(W[r,o,i]), k = il*64+ih*32+r, i = 128*ih+il ----
__global__ void prep_w(const float* __restrict__ W, const float* __restrict__ b,
                       unsigned short* __restrict__ Wb) {
  const int id = blockIdx.x * 256 + threadIdx.x;   // 256 * 2064 threads exactly
  const int o  = id / (KEXT / 4);
  const int k4 = (id - o * (KEXT / 4)) * 4;
  float v[4];
  if (k4 < KW) {
    const int r  = k4 & 31;
    const int ih = (k4 >> 5) & 1;
    const int il = k4 >> 6;
    const int i  = 128 * ih + il;
#pragma unroll
    for (int j = 0; j < 4; ++j)
      v[j] = W[((size_t)((r + j) * O_DIM + o)) * I_DIM + i];
  } else {
    const int kk = k4 - KW;
#pragma unroll
    for (int j = 0; j < 4; ++j)
      v[j] = (kk + j < R_DIM) ? b[(kk + j) * O_DIM + o] : 0.f;
  }
  uint2 pk;
  pk.x = (unsigned)f2bf(v[0]) | ((unsigned)f2bf(v[1]) << 16);
  pk.y = (unsigned)f2bf(v[2]) | ((unsigned)f2bf(v[3]) << 16);
  *(uint2*)&Wb[(size_t)o * KEXT + k4] = pk;
}

// ---- main: 512 thr, 8 waves (2M x 4N), wave tile 112x64, dbuf LDS, swizzled ----
__global__ __launch_bounds__(NTHR, 2) void lkg8(
    const float* __restrict__ x, const float* __restrict__ e,
    const unsigned short* __restrict__ Wb, float* __restrict__ out, int Ntot) {
  __shared__ unsigned short Al[2][BM * BK];   // 2 x 28 KB
  __shared__ unsigned short Bl[2][BN * BK];   // 2 x 32 KB

  const int tid  = threadIdx.x;
  const int lane = tid & 63;
  const int w    = tid >> 6;     // 0..7
  const int wr   = w >> 2;       // 0..1
  const int wc   = w & 3;        // 0..3
  const int l15  = lane & 15;

  const int  m0   = (int)blockIdx.x * BM;
  const bool stA  = (tid < 448);           // waves 0..6 stage A
  const int  srow = tid >> 1;              // 0..223
  const int  half = tid & 1;               // ih of this thread's columns
  const int  gr   = min(m0 + (stA ? srow : 0), Ntot - 1);

  // B gld_lds source-side swizzle: LDS slot (lane&7) of row gets global chunk (lane&7)^(row&7)
  const int bro = lane >> 3;              // row within 8-row group
  const int bch = (lane & 7) ^ bro;       // pre-swizzled chunk index

  // e-row cached in registers (fixed row per thread for the whole K loop)
  float er[32];
  if (stA) {
#pragma unroll
    for (int q = 0; q < 8; ++q) {
      const float4 ev = *(const float4*)&e[(size_t)gr * R_DIM + q * 4];
      er[q * 4 + 0] = ev.x; er[q * 4 + 1] = ev.y;
      er[q * 4 + 2] = ev.z; er[q * 4 + 3] = ev.w;
    }
  }
  const float* xrow = x + (size_t)gr * I_DIM + half * 128;

  f32x4 acc[7][4];
#pragma unroll
  for (int a = 0; a < 7; ++a)
#pragma unroll
    for (int c = 0; c < 4; ++c) acc[a][c] = (f32x4){0.f, 0.f, 0.f, 0.f};

  auto stageB = [&](int tn, unsigned short* Bd) {
    const size_t k0 = (size_t)tn * BK;
#pragma unroll
    for (int g = 0; g < 4; ++g) {
      gld_lds16(Wb + (size_t)(w * 32 + g * 8 + bro) * KEXT + k0 + bch * 8,
                Bd + (w * 32 + g * 8) * BK);
    }
  };
  auto stageA = [&](float xc, unsigned short* Ad) {
    if (!stA) return;
    char* rowp = (char*)(Ad + srow * BK);
    const int sw = (srow & 7) << 4;
#pragma unroll
    for (int h = 0; h < 4; ++h) {
      ushort8 pw;
#pragma unroll
      for (int j2 = 0; j2 < 8; ++j2) pw[j2] = f2bf(xc * er[h * 8 + j2]);
      *(ushort8*)(rowp + (((half * 64 + h * 16) ^ sw))) = pw;
    }
  };
  auto stageAbias = [&](unsigned short* Ad) {   // tile 128: A' = e (half 0), 0 (half 1)
    if (!stA) return;
    char* rowp = (char*)(Ad + srow * BK);
    const int sw = (srow & 7) << 4;
#pragma unroll
    for (int h = 0; h < 4; ++h) {
      ushort8 pw;
#pragma unroll
      for (int j2 = 0; j2 < 8; ++j2)
        pw[j2] = half ? (unsigned short)0 : f2bf(er[h * 8 + j2]);
      *(ushort8*)(rowp + (((half * 64 + h * 16) ^ sw))) = pw;
    }
  };
  auto compute = [&](const unsigned short* Ab, const unsigned short* Bb) {
#pragma unroll
    for (int ks = 0; ks < 2; ++ks) {
      short8 af[7];
      short8 bfr[4];
      const int kb = ks * 64 + ((lane >> 4) << 4);
      const int sx = (l15 & 7) << 4;
#pragma unroll
      for (int fr = 0; fr < 7; ++fr) {
        const int row = wr * 112 + fr * 16 + l15;
        af[fr] = *(const short8*)((const char*)Ab + row * 128 + (kb ^ sx));
      }
#pragma unroll
      for (int fc = 0; fc < 4; ++fc) {
        const int row = wc * 64 + fc * 16 + l15;
        bfr[fc] = *(const short8*)((const char*)Bb + row * 128 + (kb ^ sx));
      }
      __builtin_amdgcn_s_setprio(1);
#pragma unroll
      for (int fr = 0; fr < 7; ++fr)
#pragma unroll
        for (int fc = 0; fc < 4; ++fc)
          acc[fr][fc] = __builtin_amdgcn_mfma_f32_16x16x32_bf16(af[fr], bfr[fc],
                                                                acc[fr][fc], 0, 0, 0);
      __builtin_amdgcn_s_setprio(0);
    }
  };

  // prologue: stage tile 0 into buf 0
  float4 xv = stA ? *(const float4*)xrow : make_float4(0.f, 0.f, 0.f, 0.f);
  stageB(0, Bl[0]);
  stageA(xv.x, Al[0]);
  __syncthreads();

  for (int u = 0; u < 32; ++u) {
    float4 xvn = xv;
    if (stA && u < 31) xvn = *(const float4*)(xrow + (u + 1) * 4);
#pragma unroll
    for (int s = 0; s < 4; ++s) {
      const int t  = u * 4 + s;
      const int tn = t + 1;                       // 1..128
      unsigned short* An = Al[tn & 1];
      unsigned short* Bn = Bl[tn & 1];
      stageB(tn, Bn);
      if (s == 0)      stageA(xv.y, An);
      else if (s == 1) stageA(xv.z, An);
      else if (s == 2) stageA(xv.w, An);
      else if (u < 31) stageA(xvn.x, An);
      else             stageAbias(An);            // tn == 128
      compute(Al[t & 1], Bl[t & 1]);
      __syncthreads();
    }
    xv = xvn;
  }
  compute(Al[0], Bl[0]);                          // tile 128 (bias), no stage

  // epilogue: C layout col = lane&15, row = (lane>>4)*4 + j
#pragma unroll
  for (int fr = 0; fr < 7; ++fr) {
    const int r0 = m0 + wr * 112 + fr * 16 + (lane >> 4) * 4;
#pragma unroll
    for (int j = 0; j < 4; ++j) {
      const int rr = r0 + j;
      if (rr < Ntot) {
#pragma unroll
        for (int fc = 0; fc < 4; ++fc) {
          const int col = wc * 64 + fc * 16 + l15;
          out[(size_t)rr * O_DIM + col] = acc[fr][fc][j];
        }
      }
    }
  }
}

// ---- fallback (ws too small): round-1 kernel reading W/b directly ----
__global__ __launch_bounds__(256, 2) void lkg_fb(
    const float* __restrict__ x, const float* __restrict__ e,
    const float* __restrict__ Wf, const float* __restrict__ bf32,
    float* __restrict__ out, int Ntot) {
  const int FBM = 128, FBN = 256, FBK = 64;
  const int FNT = (KW + 64) / FBK;                 // 129, r-major mapping
  __shared__ unsigned short Alds[128 * 64];
  __shared__ unsigned short Blds[256 * 64];

  const int tid = threadIdx.x, lane = tid & 63, wid = tid >> 6;
  const int wr = wid >> 1, wc = wid & 1, l15 = lane & 15, lk8 = (lane >> 4) * 8;
  const int m0 = (int)blockIdx.x * FBM;
  const int srow = tid >> 1, skq = (tid & 1) * 32;
  const int gr = min(m0 + srow, Ntot - 1);

  f32x4 acc[4][8];
#pragma unroll
  for (int a = 0; a < 4; ++a)
#pragma unroll
    for (int c = 0; c < 8; ++c) acc[a][c] = (f32x4){0.f, 0.f, 0.f, 0.f};

  for (int t = 0; t < FNT; ++t) {
    const int k0 = t * FBK;
    float av[32];
    if (k0 < KW) {
      const int r = k0 >> 8, i0 = k0 & 255;
      const float ev = e[(size_t)gr * R_DIM + r];
#pragma unroll
      for (int q = 0; q < 8; ++q) {
        const float4 xvv = *(const float4*)&x[(size_t)gr * I_DIM + i0 + skq + q * 4];
        av[q * 4 + 0] = xvv.x * ev; av[q * 4 + 1] = xvv.y * ev;
        av[q * 4 + 2] = xvv.z * ev; av[q * 4 + 3] = xvv.w * ev;
      }
    } else {
#pragma unroll
      for (int s2 = 0; s2 < 32; ++s2) {
        const int kk = skq + s2;
        av[s2] = (kk < R_DIM) ? e[(size_t)gr * R_DIM + kk] : 0.f;
      }
    }
    const int bo = tid;
    if (k0 < KW) {
      const int r = k0 >> 8, i0 = k0 & 255;
#pragma unroll
      for (int h = 0; h < 4; ++h) {
        float bv[16];
#pragma unroll
        for (int q = 0; q < 4; ++q) {
          const float4 wv =
              *(const float4*)&Wf[((size_t)(r * O_DIM + bo)) * I_DIM + i0 + h * 16 + q * 4];
          bv[q * 4 + 0] = wv.x; bv[q * 4 + 1] = wv.y;
          bv[q * 4 + 2] = wv.z; bv[q * 4 + 3] = wv.w;
        }
#pragma unroll
        for (int g2 = 0; g2 < 2; ++g2) {
          ushort8 pw;
#pragma unroll
          for (int j = 0; j < 8; ++j) pw[j] = f2bf(bv[g2 * 8 + j]);
          *(ushort8*)&Blds[bo * FBK + h * 16 + g2 * 8] = pw;
        }
      }
    } else {
#pragma unroll
      for (int h = 0; h < 8; ++h) {
        ushort8 pw;
#pragma unroll
        for (int j = 0; j < 8; ++j) {
          const int kk = h * 8 + j;
          pw[j] = (kk < R_DIM) ? f2bf(bf32[kk * O_DIM + bo]) : (unsigned short)0;
        }
        *(ushort8*)&Blds[bo * FBK + h * 8] = pw;
      }
    }
#pragma unroll
    for (int h = 0; h < 4; ++h) {
      ushort8 pw;
#pragma unroll
      for (int j = 0; j < 8; ++j) pw[j] = f2bf(av[h * 8 + j]);
      *(ushort8*)&Alds[srow * FBK + skq + h * 8] = pw;
    }
    __syncthreads();
#pragma unroll
    for (int ks = 0; ks < 2; ++ks) {
      short8 af[4]; short8 bfr[8];
#pragma unroll
      for (int fr = 0; fr < 4; ++fr)
        af[fr] = *(const short8*)&Alds[(wr * 64 + fr * 16 + l15) * FBK + ks * 32 + lk8];
#pragma unroll
      for (int fc = 0; fc < 8; ++fc)
        bfr[fc] = *(const short8*)&Blds[(wc * 128 + fc * 16 + l15) * FBK + ks * 32 + lk8];
#pragma unroll
      for (int fr = 0; fr < 4; ++fr)
#pragma unroll
        for (int fc = 0; fc < 8; ++fc)
          acc[fr][fc] =
              __builtin_amdgcn_mfma_f32_16x16x32_bf16(af[fr], bfr[fc], acc[fr][fc], 0, 0, 0);
    }
    __syncthreads();
  }
#pragma unroll
  for (int fr = 0; fr < 4; ++fr) {
    const int r0 = m0 + wr * 64 + fr * 16 + (lane >> 4) * 4;
#pragma unroll
    for (int fc = 0; fc < 8; ++fc) {
      const int col = wc * 128 + fc * 16 + l15;
#pragma unroll
      for (int j = 0; j < 4; ++j) {
        const int rr = r0 + j;
        if (rr < Ntot) out[(size_t)rr * O_DIM + col] = acc[fr][fc][j];
      }
    }
  }
}

extern "C" void kernel_launch(void* const* d_in, const int* in_sizes, int n_in,
                              void* d_out, int out_size, void* d_ws, size_t ws_size,
                              hipStream_t stream) {
  const float* x = (const float*)d_in[0];
  const float* e = (const float*)d_in[1];
  const float* W = (const float*)d_in[2];
  const float* b = (const float*)d_in[3];
  float* out = (float*)d_out;
  const int Ntot = in_sizes[0] / I_DIM;

  const size_t wb_bytes = (size_t)O_DIM * KEXT * sizeof(unsigned short);
  if (ws_size >= wb_bytes) {
    unsigned short* Wb = (unsigned short*)d_ws;
    prep_w<<<(O_DIM * (KEXT / 4)) / 256, 256, 0, stream>>>(W, b, Wb);
    lkg8<<<(Ntot + BM - 1) / BM, NTHR, 0, stream>>>(x, e, Wb, out, Ntot);
  } else {
    lkg_fb<<<(Ntot + 127) / 128, 256, 0, stream>>>(x, e, W, b, out, Ntot);
  }
}